// Round 10
// baseline (210.456 us; speedup 1.0000x reference)
//
#include <hip/hip_runtime.h>

#define SEQ 2048
#define HID 2048
#define NH  32
#define NKV 8
#define HD  64

typedef _Float16 f16;
typedef __attribute__((ext_vector_type(4))) _Float16 f16x4;
typedef __attribute__((ext_vector_type(8))) _Float16 f16x8;
typedef __attribute__((ext_vector_type(2))) __fp16   h16x2;
typedef __attribute__((ext_vector_type(4))) float    f32x4;

__device__ __forceinline__ f32x4 mfma_16x16x32(f16x8 a, f16x8 b, f32x4 c) {
    return __builtin_amdgcn_mfma_f32_16x16x32_f16(a, b, c, 0, 0, 0);
}

// async global->LDS, 16B per lane. Global address is PER-LANE (gather);
// LDS dest is wave-uniform base + lane*16 (contiguous).
__device__ __forceinline__ void async16(const void* g, void* l) {
    __builtin_amdgcn_global_load_lds(
        (const __attribute__((address_space(1))) void*)g,
        (__attribute__((address_space(3))) void*)l,
        16, 0, 0);
}

// Bijective XCD remap, column-chunked (m204 variant).
__device__ __forceinline__ void xcd_colmap(int& bx, int& by) {
    int gx = gridDim.x, gy = gridDim.y;
    int nwg = gx * gy;
    int orig = by * gx + bx;
    int q = nwg >> 3, r = nwg & 7;
    int xcd = orig & 7, loc = orig >> 3;
    int wg = (xcd < r ? xcd * (q + 1) : r * (q + 1) + (xcd - r) * q) + loc;
    bx = wg / gy;
    by = wg - bx * gy;
}

// ---------------- prep: vectorized transposes + cvt (G13) ----------------------
__global__ void prep_all(const float* __restrict__ x,
                         const float* __restrict__ wq, const float* __restrict__ wk,
                         const float* __restrict__ wv, const float* __restrict__ wo,
                         f16* __restrict__ xb,
                         f16* __restrict__ Wcat, f16* __restrict__ woT) {
    __shared__ float ft[64 * 65];
    int z = blockIdx.z;
    int tid = threadIdx.x;            // 256 threads
    if (z == 4) {                     // cvt: 2048*2048 flat, grid (32,32)
        int base = (blockIdx.y * 32 + blockIdx.x) * 4096 + tid * 8;
#pragma unroll
        for (int i = 0; i < 2; i++) {
            int off = base + i * 2048;
            float4 a = *(const float4*)(x + off);
            float4 b = *(const float4*)(x + off + 4);
            f16x8 o = { (f16)a.x, (f16)a.y, (f16)a.z, (f16)a.w,
                        (f16)b.x, (f16)b.y, (f16)b.z, (f16)b.w };
            *(f16x8*)(xb + off) = o;
        }
        return;
    }
    const float* src; f16* dst; int C;
    if      (z == 0) { src = wq; dst = Wcat;                         C = 2048; }
    else if (z == 1) { src = wk; dst = Wcat + (size_t)2048 * 2048;   C = 512;  }
    else if (z == 2) { src = wv; dst = Wcat + (size_t)2560 * 2048;   C = 512;  }
    else             { src = wo; dst = woT;                          C = 2048; }
    int c0 = blockIdx.x * 64, r0 = blockIdx.y * 64;
    if (c0 >= C) return;
    int c4 = tid & 15;
#pragma unroll
    for (int i = 0; i < 4; i++) {
        int r = (tid >> 4) * 4 + i;
        float4 v = *(const float4*)(src + (size_t)(r0 + r) * C + c0 + c4 * 4);
        *(float4*)(&ft[r * 65 + c4 * 4]) = v;
    }
    __syncthreads();
    int q = tid & 7;
#pragma unroll
    for (int it = 0; it < 2; it++) {
        int jj = (tid >> 3) + it * 32;
        f16x8 v;
#pragma unroll
        for (int e = 0; e < 8; e++)
            v[e] = (f16)ft[(q * 8 + e) * 65 + jj];
        *(f16x8*)(dst + (size_t)(c0 + jj) * 2048 + r0 + q * 8) = v;
    }
}

// ---------------- GEMM: C[M,N] = A[M,K] @ BT[N,K]^T (round-1 known-good) -------
// BM x 128 tile, BK=64, 4 waves 2x2, dbuf staging with XOR-swizzled k-chunks.
// Plain __syncthreads loop (pins/setprio regressed — m141/m190). BM=64 both.
template <int MODE, int BM>
__global__ __launch_bounds__(256)
void gemm_bt(const f16* __restrict__ A, const f16* __restrict__ BT,
             float* __restrict__ Cf, f16* __restrict__ Q, f16* __restrict__ Kk,
             f16* __restrict__ VT, const int* __restrict__ pos,
             const float* __restrict__ mask, int N, int K) {
    constexpr int MI = BM / 32;      // acc rows / af frags per wave
    constexpr int AR = BM / 4;       // A rows staged per wave
    __shared__ f16 As[2][BM * 64];   // [row][k-chunk swizzled]
    __shared__ f16 Bs[2][128 * 64];
    int t = threadIdx.x;
    int w = t >> 6, lane = t & 63, quad = lane >> 4, l15 = lane & 15;
    int wm = w >> 1, wn = w & 1;
    int bx = blockIdx.x, by = blockIdx.y;
    xcd_colmap(bx, by);
    int m0 = by * BM, n0 = bx * 128;
    int sw = l15 & 7;

    int r8 = lane >> 3;            // row within 8-row staging group
    int cc = (lane & 7) ^ r8;      // XOR-swizzled global k-chunk
    const f16* Ag = A  + (size_t)(m0 + w * AR + r8) * K + cc * 8;
    const f16* Bg = BT + (size_t)(n0 + w * 32 + r8) * K + cc * 8;

    f32x4 acc[MI][4] = {};

    // stage tile 0
#pragma unroll
    for (int a = 0; a < AR / 8; a++)
        async16(Ag + (size_t)(8 * a) * K, &As[0][(w * AR + 8 * a) * 64]);
#pragma unroll
    for (int g = 0; g < 4; g++)
        async16(Bg + (size_t)(8 * g) * K, &Bs[0][(w * 32 + 8 * g) * 64]);
    __syncthreads();

    int b = 0;
    for (int kt = 64; kt <= K; kt += 64) {
        if (kt < K) {
#pragma unroll
            for (int a = 0; a < AR / 8; a++)
                async16(Ag + (size_t)(8 * a) * K + kt, &As[b ^ 1][(w * AR + 8 * a) * 64]);
#pragma unroll
            for (int g = 0; g < 4; g++)
                async16(Bg + (size_t)(8 * g) * K + kt, &Bs[b ^ 1][(w * 32 + 8 * g) * 64]);
        }
        f16x8 af[MI][2], bf[4][2];
#pragma unroll
        for (int mi = 0; mi < MI; mi++) {
            int row = wm * (BM / 2) + mi * 16 + l15;
#pragma unroll
            for (int kh = 0; kh < 2; kh++)
                af[mi][kh] = *(const f16x8*)(&As[b][row * 64 + ((kh * 4 + quad) ^ sw) * 8]);
        }
#pragma unroll
        for (int ni = 0; ni < 4; ni++) {
            int row = wn * 64 + ni * 16 + l15;
#pragma unroll
            for (int kh = 0; kh < 2; kh++)
                bf[ni][kh] = *(const f16x8*)(&Bs[b][row * 64 + ((kh * 4 + quad) ^ sw) * 8]);
        }
#pragma unroll
        for (int mi = 0; mi < MI; mi++)
#pragma unroll
            for (int ni = 0; ni < 4; ni++) {
                acc[mi][ni] = mfma_16x16x32(af[mi][0], bf[ni][0], acc[mi][ni]);
                acc[mi][ni] = mfma_16x16x32(af[mi][1], bf[ni][1], acc[mi][ni]);
            }
        __syncthreads();
        b ^= 1;
    }

    int rb  = m0 + wm * (BM / 2) + quad * 4;
    int cbh = n0 + wn * 64;          // 64-aligned: one head per wave column
    if (MODE == 0) {
        if (cbh < (NH + NKV) * HD) {
            bool isQ = cbh < NH * HD;
            f16* dst = isQ ? (Q  + (size_t)(cbh >> 6) * SEQ * HD)
                           : (Kk + (size_t)((cbh - NH * HD) >> 6) * SEQ * HD);
            float scale = isQ ? 0.18033688011112042f : 1.0f;  // (1/8)*log2(e)
            float fr[2];
#pragma unroll
            for (int ni = 0; ni < 2; ni++)
                fr[ni] = __builtin_amdgcn_exp2f(
                    (float)(ni * 16 + l15) * -0.41524101186092029f); // -log2(1e4)/32
#pragma unroll
            for (int mi = 0; mi < MI; mi++)
#pragma unroll
                for (int r = 0; r < 4; r++) {
                    int row = rb + mi * 16 + r;
                    float pv = (float)pos[row];
#pragma unroll
                    for (int ni = 0; ni < 2; ni++) {
                        float sn, cs;
                        __sincosf(pv * fr[ni], &sn, &cs);
                        float x1 = acc[mi][ni][r], x2 = acc[mi][ni + 2][r];
                        int d = ni * 16 + l15;
                        dst[(size_t)row * HD + d]      = (f16)(scale * (x1 * cs - x2 * sn));
                        dst[(size_t)row * HD + d + 32] = (f16)(scale * (x2 * cs + x1 * sn));
                    }
                }
        } else {
            // ---- V^T with mask folded in: VT[c2][s] = v * exp2(mask[s]*log2e).
            const float LOG2E = 1.4426950408889634f;
#pragma unroll
            for (int mi = 0; mi < MI; mi++) {
                float4 mv = *(const float4*)(mask + rb + mi * 16);
                float em[4];
#pragma unroll
                for (int r = 0; r < 4; r++)
                    em[r] = __builtin_amdgcn_exp2f((&mv.x)[r] * LOG2E);
#pragma unroll
                for (int ni = 0; ni < 4; ni++) {
                    int c2 = cbh - (NH + NKV) * HD + ni * 16 + l15;
                    f16x4 v4;
                    ((h16x2*)&v4)[0] = __builtin_amdgcn_cvt_pkrtz(
                        acc[mi][ni][0] * em[0], acc[mi][ni][1] * em[1]);
                    ((h16x2*)&v4)[1] = __builtin_amdgcn_cvt_pkrtz(
                        acc[mi][ni][2] * em[2], acc[mi][ni][3] * em[3]);
                    *(f16x4*)(VT + (size_t)c2 * SEQ + rb + mi * 16) = v4;
                }
            }
        }
    } else {
#pragma unroll
        for (int mi = 0; mi < MI; mi++)
#pragma unroll
            for (int ni = 0; ni < 4; ni++)
#pragma unroll
                for (int r = 0; r < 4; r++)
                    Cf[(size_t)(rb + mi * 16 + r) * N + cbh + ni * 16 + l15] =
                        acc[mi][ni][r];
    }
}

// ---------------- fused flash attention: 2 tiles per barrier, ring-6 -----------
// grid (SEQ/256, NH) = 256 blocks x 512 threads. Round-5 symmetric 8-wave
// staging (waves 0-3 K permuted-rows g(), waves 4-7 V^T; 2 async16/wave/tile).
// RING of 6 slots, ONE barrier per TWO tiles: iteration i stages tiles
// 2i+2,2i+3 (overwriting tiles 2i-4,2i-3 — computed in iteration i-2,
// strictly before barrier(i-1): one full barrier of separation; ring-4
// would race). vmcnt(4) leaves only the 4 newest loads (t+2,t+3) in
// flight; in-order vmcnt retire guarantees tiles t,t+1 + Q/Em loads
// landed. The 2-tile straight-line body halves barrier count (round-3
// isolated this at ~3.5us, there eaten by bank conflicts — here rows
// stay 64-f16 wide, conflicts 0) and gives the compiler a cross-tile
// scheduling window (hoist tile t+1 ds_reads into tile t's MFMA shadow).
// LDS = 100 KB.
__global__ __launch_bounds__(512)
void attn_fused(const f16* __restrict__ Qb, const f16* __restrict__ Kb,
                const f16* __restrict__ VTb, const float* __restrict__ mask,
                f16* __restrict__ ctx) {
    __shared__ f16 Ks[6][64 * 64];
    __shared__ f16 Vs[6][64 * 64];
    __shared__ f16 Em[SEQ];

    int t = threadIdx.x, w = t >> 6, lane = t & 63, quad = lane >> 4, l15 = lane & 15;
    int h = blockIdx.y, kvh = h >> 2;
    int qbase = blockIdx.x * 256 + w * 32;
    const f16* Qh = Qb  + (size_t)h   * SEQ * HD;
    const f16* Kh = Kb  + (size_t)kvh * SEQ * HD;
    const f16* Vh = VTb + (size_t)kvh * HD * SEQ;
    int sw = l15 & 7;
    const float LOG2E = 1.4426950408889634f;

    // ---- staging: wave role. K waves use permuted rows (g(rr)=k_eff). ----
    int r8 = lane >> 3;
    int cc = (lane & 7) ^ r8;
    bool isK = w < 4;
    int ws = isK ? w : (w - 4);
    const f16* g0;
    long gstep;
    if (isK) {
        int gk = 32 * (ws >> 1) + 4 * (ws & 1) + 8 * (r8 >> 2) + (r8 & 3);
        g0 = Kh + (size_t)gk * HD + cc * 8;
        gstep = (long)16 * HD;       // second async16: keys g+16
    } else {
        g0 = Vh + (size_t)(ws * 16 + r8) * SEQ + cc * 8;
        gstep = (long)8 * SEQ;       // second async16: rows +8
    }
    const f16* g1 = g0 + gstep;
    long adv = isK ? (long)64 * HD : 64;
    int lr0 = ws * 16 * 64, lr1 = lr0 + 8 * 64;

    {   // prologue: stage tiles 0 (slot 0) and 1 (slot 1)
        f16* d0 = (isK ? &Ks[0][0] : &Vs[0][0]);
        async16(g0, d0 + lr0);
        async16(g1, d0 + lr1);
        g0 += adv; g1 += adv;
        f16* d1 = (isK ? &Ks[1][0] : &Vs[1][0]);
        async16(g0, d1 + lr0);
        async16(g1, d1 + lr1);
    }

    // ---- stage em = exp2(mask*log2e) for full SEQ (one f16x4 per thread) ----
    {
        int idx = t * 4;
        float4 mv = *(const float4*)(mask + idx);
        f16x4 e;
        ((h16x2*)&e)[0] = __builtin_amdgcn_cvt_pkrtz(
            __builtin_amdgcn_exp2f(mv.x * LOG2E), __builtin_amdgcn_exp2f(mv.y * LOG2E));
        ((h16x2*)&e)[1] = __builtin_amdgcn_cvt_pkrtz(
            __builtin_amdgcn_exp2f(mv.z * LOG2E), __builtin_amdgcn_exp2f(mv.w * LOG2E));
        *(f16x4*)(&Em[idx]) = e;
    }

    // ---- Q fragments (persistent): B-operand of S^T, n = q ----
    f16x8 bq[2][2];
#pragma unroll
    for (int qg = 0; qg < 2; qg++)
#pragma unroll
        for (int ks = 0; ks < 2; ks++)
            bq[qg][ks] = *(const f16x8*)(Qh + (size_t)(qbase + qg * 16 + l15) * HD
                                            + ks * 32 + quad * 8);

    f32x4 o[4][2] = {};          // O^T: [d-tile][q-group]
    f32x4 ol[2]   = {};          // l accumulator (all rows identical)

    int c0 = (quad ^ sw) * 8, c1 = ((4 | quad) ^ sw) * 8;

    // one-tile compute body (slot = tile's ring slot)
    auto tilecomp = [&](int tt, int slot) {
        const f16* Kb_ = &Ks[slot][0];
        const f16* Vb_ = &Vs[slot][0];
        // ---- S^T = K @ Q^T (keys in permuted order) ----
        f32x4 st[4][2] = {};
        __builtin_amdgcn_s_setprio(1);
#pragma unroll
        for (int ni = 0; ni < 4; ni++) {
            const f16* kr = Kb_ + (ni * 16 + l15) * 64;
            f16x8 ak0 = *(const f16x8*)(kr + c0);
            f16x8 ak1 = *(const f16x8*)(kr + c1);
#pragma unroll
            for (int qg = 0; qg < 2; qg++) {
                st[ni][qg] = mfma_16x16x32(ak0, bq[qg][0], st[ni][qg]);
                st[ni][qg] = mfma_16x16x32(ak1, bq[qg][1], st[ni][qg]);
            }
        }
        __builtin_amdgcn_s_setprio(0);
        // ---- p = exp2(s); pack via cvt_pkrtz ----
        f16x8 pb[2][2];
#pragma unroll
        for (int ni = 0; ni < 4; ni++)
#pragma unroll
            for (int qg = 0; qg < 2; qg++) {
                h16x2 lo = __builtin_amdgcn_cvt_pkrtz(
                    __builtin_amdgcn_exp2f(st[ni][qg][0]),
                    __builtin_amdgcn_exp2f(st[ni][qg][1]));
                h16x2 hi = __builtin_amdgcn_cvt_pkrtz(
                    __builtin_amdgcn_exp2f(st[ni][qg][2]),
                    __builtin_amdgcn_exp2f(st[ni][qg][3]));
                ((h16x2*)&pb[qg][ni >> 1])[(ni & 1) * 2]     = lo;
                ((h16x2*)&pb[qg][ni >> 1])[(ni & 1) * 2 + 1] = hi;
            }
        // ---- l += em-row @ P ----
        f16x8 em0 = *(const f16x8*)(&Em[tt * 64 + quad * 8]);
        f16x8 em1 = *(const f16x8*)(&Em[tt * 64 + 32 + quad * 8]);
        __builtin_amdgcn_s_setprio(1);
#pragma unroll
        for (int qg = 0; qg < 2; qg++) {
            ol[qg] = mfma_16x16x32(em0, pb[qg][0], ol[qg]);
            ol[qg] = mfma_16x16x32(em1, pb[qg][1], ol[qg]);
        }
        // ---- O^T += V^T @ P ----
#pragma unroll
        for (int dt = 0; dt < 4; dt++) {
            const f16* vr = Vb_ + (dt * 16 + l15) * 64;
            f16x8 av0 = *(const f16x8*)(vr + c0);
            f16x8 av1 = *(const f16x8*)(vr + c1);
#pragma unroll
            for (int qg = 0; qg < 2; qg++) {
                o[dt][qg] = mfma_16x16x32(av0, pb[qg][0], o[dt][qg]);
                o[dt][qg] = mfma_16x16x32(av1, pb[qg][1], o[dt][qg]);
            }
        }
        __builtin_amdgcn_s_setprio(0);
    };

    // Em ds_writes drained before the first barrier publishes them
    asm volatile("s_waitcnt lgkmcnt(0)" ::: "memory");

    const int NT = SEQ / 64;     // 32 tiles, 16 barrier iterations
    int sc = 0;                  // ring slot of tile ktl (cycles 0,2,4)
    for (int ktl = 0; ktl < NT; ktl += 2) {
        int sn = sc + 2; if (sn >= 6) sn -= 6;   // slot of tile ktl+2
        if (ktl + 2 < NT) {
            g0 += adv; g1 += adv;
            f16* d0 = (isK ? &Ks[sn][0] : &Vs[sn][0]);
            async16(g0, d0 + lr0);
            async16(g1, d0 + lr1);
            g0 += adv; g1 += adv;
            f16* d1 = (isK ? &Ks[sn + 1][0] : &Vs[sn + 1][0]);
            async16(g0, d1 + lr0);
            async16(g1, d1 + lr1);
            // tiles t,t+1's 4 loads are oldest; only the 4 new may remain
            asm volatile("s_waitcnt vmcnt(4)" ::: "memory");
        } else {
            asm volatile("s_waitcnt vmcnt(0)" ::: "memory");
        }
        __builtin_amdgcn_sched_barrier(0);
        __builtin_amdgcn_s_barrier();            // tiles t,t+1 landed for all
        __builtin_amdgcn_sched_barrier(0);       // pin: no ds_read hoists above

        tilecomp(ktl,     sc);
        tilecomp(ktl + 1, sc + 1);

        sc = sn;
    }

    // ---- normalize in-register, write ctx[row][h*64+d] directly ----
    float inv[2] = { 1.0f / ol[0][0], 1.0f / ol[1][0] };
#pragma unroll
    for (int dt = 0; dt < 4; dt++)
#pragma unroll
        for (int qg = 0; qg < 2; qg++) {
            f16x4 v4;
            ((h16x2*)&v4)[0] = __builtin_amdgcn_cvt_pkrtz(
                o[dt][qg][0] * inv[qg], o[dt][qg][1] * inv[qg]);
            ((h16x2*)&v4)[1] = __builtin_amdgcn_cvt_pkrtz(
                o[dt][qg][2] * inv[qg], o[dt][qg][3] * inv[qg]);
            *(f16x4*)(ctx + (size_t)(qbase + qg * 16 + l15) * (NH * HD)
                          + h * HD + dt * 16 + quad * 4) = v4;
        }
}

// ---------------- launch ----------------
extern "C" void kernel_launch(void* const* d_in, const int* in_sizes, int n_in,
                              void* d_out, int out_size, void* d_ws, size_t ws_size,
                              hipStream_t stream) {
    const float* x    = (const float*)d_in[0];
    const float* mask = (const float*)d_in[1];
    const int*   pos  = (const int*)  d_in[2];
    const float* wq   = (const float*)d_in[3];
    const float* wk   = (const float*)d_in[4];
    const float* wv   = (const float*)d_in[5];
    const float* wo   = (const float*)d_in[6];
    float* out = (float*)d_out;

    char* ws = (char*)d_ws;
    // phase 1-2: xb [0,8M), Wcat [8,20M), woT [20,28M), Qb [28,36M),
    //            Kb [36,38M), VTb [38,40M)
    // phase 3:   ctx [0,8M) (xb dead after gemm0)
    // phase 4:   gemm1 reads ctx + woT
    f16*   xb    = (f16*)(ws);
    f16*   Wcat  = (f16*)(ws + ((size_t)8  << 20));
    f16*   woT   = (f16*)(ws + ((size_t)20 << 20));
    f16*   Qb    = (f16*)(ws + ((size_t)28 << 20));
    f16*   Kb    = (f16*)(ws + ((size_t)36 << 20));
    f16*   VTb   = (f16*)(ws + ((size_t)38 << 20));
    f16*   ctx   = (f16*)(ws);

    prep_all<<<dim3(32, 32, 5), 256, 0, stream>>>(
        x, wq, wk, wv, wo, xb, Wcat, woT);

    // fused Q/K/V projection + RoPE + mask-folded V: C[2048,3072] = xb @ Wcat^T
    gemm_bt<0, 64><<<dim3(3072 / 128, 2048 / 64), 256, 0, stream>>>(
        xb, Wcat, nullptr, Qb, Kb, VTb, pos, mask, 3072, 2048);

    attn_fused<<<dim3(SEQ / 256, NH), 512, 0, stream>>>(
        Qb, Kb, VTb, mask, ctx);

    // out = ctx @ wo (fp32 direct)
    gemm_bt<1, 64><<<dim3(2048 / 128, 2048 / 64), 256, 0, stream>>>(
        ctx, woT, out, nullptr, nullptr, nullptr, nullptr, nullptr, 2048, 2048);
}

// Round 11
// 204.065 us; speedup vs baseline: 1.0313x; 1.0313x over previous
//
#include <hip/hip_runtime.h>

#define SEQ 2048
#define HID 2048
#define NH  32
#define NKV 8
#define HD  64

typedef _Float16 f16;
typedef __attribute__((ext_vector_type(4))) _Float16 f16x4;
typedef __attribute__((ext_vector_type(8))) _Float16 f16x8;
typedef __attribute__((ext_vector_type(2))) __fp16   h16x2;
typedef __attribute__((ext_vector_type(4))) float    f32x4;

__device__ __forceinline__ f32x4 mfma_16x16x32(f16x8 a, f16x8 b, f32x4 c) {
    return __builtin_amdgcn_mfma_f32_16x16x32_f16(a, b, c, 0, 0, 0);
}

// async global->LDS, 16B per lane. Global address is PER-LANE (gather);
// LDS dest is wave-uniform base + lane*16 (contiguous).
__device__ __forceinline__ void async16(const void* g, void* l) {
    __builtin_amdgcn_global_load_lds(
        (const __attribute__((address_space(1))) void*)g,
        (__attribute__((address_space(3))) void*)l,
        16, 0, 0);
}

// Bijective XCD remap, column-chunked (m204 variant).
__device__ __forceinline__ void xcd_colmap(int& bx, int& by) {
    int gx = gridDim.x, gy = gridDim.y;
    int nwg = gx * gy;
    int orig = by * gx + bx;
    int q = nwg >> 3, r = nwg & 7;
    int xcd = orig & 7, loc = orig >> 3;
    int wg = (xcd < r ? xcd * (q + 1) : r * (q + 1) + (xcd - r) * q) + loc;
    bx = wg / gy;
    by = wg - bx * gy;
}

// ---------------- prep: vectorized transposes + cvt (G13) ----------------------
__global__ void prep_all(const float* __restrict__ x,
                         const float* __restrict__ wq, const float* __restrict__ wk,
                         const float* __restrict__ wv, const float* __restrict__ wo,
                         f16* __restrict__ xb,
                         f16* __restrict__ Wcat, f16* __restrict__ woT) {
    __shared__ float ft[64 * 65];
    int z = blockIdx.z;
    int tid = threadIdx.x;            // 256 threads
    if (z == 4) {                     // cvt: 2048*2048 flat, grid (32,32)
        int base = (blockIdx.y * 32 + blockIdx.x) * 4096 + tid * 8;
#pragma unroll
        for (int i = 0; i < 2; i++) {
            int off = base + i * 2048;
            float4 a = *(const float4*)(x + off);
            float4 b = *(const float4*)(x + off + 4);
            f16x8 o = { (f16)a.x, (f16)a.y, (f16)a.z, (f16)a.w,
                        (f16)b.x, (f16)b.y, (f16)b.z, (f16)b.w };
            *(f16x8*)(xb + off) = o;
        }
        return;
    }
    const float* src; f16* dst; int C;
    if      (z == 0) { src = wq; dst = Wcat;                         C = 2048; }
    else if (z == 1) { src = wk; dst = Wcat + (size_t)2048 * 2048;   C = 512;  }
    else if (z == 2) { src = wv; dst = Wcat + (size_t)2560 * 2048;   C = 512;  }
    else             { src = wo; dst = woT;                          C = 2048; }
    int c0 = blockIdx.x * 64, r0 = blockIdx.y * 64;
    if (c0 >= C) return;
    int c4 = tid & 15;
#pragma unroll
    for (int i = 0; i < 4; i++) {
        int r = (tid >> 4) * 4 + i;
        float4 v = *(const float4*)(src + (size_t)(r0 + r) * C + c0 + c4 * 4);
        *(float4*)(&ft[r * 65 + c4 * 4]) = v;
    }
    __syncthreads();
    int q = tid & 7;
#pragma unroll
    for (int it = 0; it < 2; it++) {
        int jj = (tid >> 3) + it * 32;
        f16x8 v;
#pragma unroll
        for (int e = 0; e < 8; e++)
            v[e] = (f16)ft[(q * 8 + e) * 65 + jj];
        *(f16x8*)(dst + (size_t)(c0 + jj) * 2048 + r0 + q * 8) = v;
    }
}

// ---------------- GEMM: C[M,N] = A[M,K] @ BT[N,K]^T (round-1 known-good) -------
// BM x 128 tile, BK=64, 4 waves 2x2, dbuf staging with XOR-swizzled k-chunks.
// Plain __syncthreads loop (pins/setprio regressed — m141/m190). BM=64 both.
// Near its structural floor for these shapes: MFMA floor 12.4us + LDS floor
// ~15-23us serialized + drain ≈ measured ~38us; deeper rings cost the
// 3-blocks/CU residency (48KB x ring-4 = 96KB), measured worse (round 4).
template <int MODE, int BM>
__global__ __launch_bounds__(256)
void gemm_bt(const f16* __restrict__ A, const f16* __restrict__ BT,
             float* __restrict__ Cf, f16* __restrict__ Q, f16* __restrict__ Kk,
             f16* __restrict__ VT, const int* __restrict__ pos,
             const float* __restrict__ mask, int N, int K) {
    constexpr int MI = BM / 32;      // acc rows / af frags per wave
    constexpr int AR = BM / 4;       // A rows staged per wave
    __shared__ f16 As[2][BM * 64];   // [row][k-chunk swizzled]
    __shared__ f16 Bs[2][128 * 64];
    int t = threadIdx.x;
    int w = t >> 6, lane = t & 63, quad = lane >> 4, l15 = lane & 15;
    int wm = w >> 1, wn = w & 1;
    int bx = blockIdx.x, by = blockIdx.y;
    xcd_colmap(bx, by);
    int m0 = by * BM, n0 = bx * 128;
    int sw = l15 & 7;

    int r8 = lane >> 3;            // row within 8-row staging group
    int cc = (lane & 7) ^ r8;      // XOR-swizzled global k-chunk
    const f16* Ag = A  + (size_t)(m0 + w * AR + r8) * K + cc * 8;
    const f16* Bg = BT + (size_t)(n0 + w * 32 + r8) * K + cc * 8;

    f32x4 acc[MI][4] = {};

    // stage tile 0
#pragma unroll
    for (int a = 0; a < AR / 8; a++)
        async16(Ag + (size_t)(8 * a) * K, &As[0][(w * AR + 8 * a) * 64]);
#pragma unroll
    for (int g = 0; g < 4; g++)
        async16(Bg + (size_t)(8 * g) * K, &Bs[0][(w * 32 + 8 * g) * 64]);
    __syncthreads();

    int b = 0;
    for (int kt = 64; kt <= K; kt += 64) {
        if (kt < K) {
#pragma unroll
            for (int a = 0; a < AR / 8; a++)
                async16(Ag + (size_t)(8 * a) * K + kt, &As[b ^ 1][(w * AR + 8 * a) * 64]);
#pragma unroll
            for (int g = 0; g < 4; g++)
                async16(Bg + (size_t)(8 * g) * K + kt, &Bs[b ^ 1][(w * 32 + 8 * g) * 64]);
        }
        f16x8 af[MI][2], bf[4][2];
#pragma unroll
        for (int mi = 0; mi < MI; mi++) {
            int row = wm * (BM / 2) + mi * 16 + l15;
#pragma unroll
            for (int kh = 0; kh < 2; kh++)
                af[mi][kh] = *(const f16x8*)(&As[b][row * 64 + ((kh * 4 + quad) ^ sw) * 8]);
        }
#pragma unroll
        for (int ni = 0; ni < 4; ni++) {
            int row = wn * 64 + ni * 16 + l15;
#pragma unroll
            for (int kh = 0; kh < 2; kh++)
                bf[ni][kh] = *(const f16x8*)(&Bs[b][row * 64 + ((kh * 4 + quad) ^ sw) * 8]);
        }
#pragma unroll
        for (int mi = 0; mi < MI; mi++)
#pragma unroll
            for (int ni = 0; ni < 4; ni++) {
                acc[mi][ni] = mfma_16x16x32(af[mi][0], bf[ni][0], acc[mi][ni]);
                acc[mi][ni] = mfma_16x16x32(af[mi][1], bf[ni][1], acc[mi][ni]);
            }
        __syncthreads();
        b ^= 1;
    }

    int rb  = m0 + wm * (BM / 2) + quad * 4;
    int cbh = n0 + wn * 64;          // 64-aligned: one head per wave column
    if (MODE == 0) {
        if (cbh < (NH + NKV) * HD) {
            bool isQ = cbh < NH * HD;
            f16* dst = isQ ? (Q  + (size_t)(cbh >> 6) * SEQ * HD)
                           : (Kk + (size_t)((cbh - NH * HD) >> 6) * SEQ * HD);
            float scale = isQ ? 0.18033688011112042f : 1.0f;  // (1/8)*log2(e)
            float fr[2];
#pragma unroll
            for (int ni = 0; ni < 2; ni++)
                fr[ni] = __builtin_amdgcn_exp2f(
                    (float)(ni * 16 + l15) * -0.41524101186092029f); // -log2(1e4)/32
#pragma unroll
            for (int mi = 0; mi < MI; mi++)
#pragma unroll
                for (int r = 0; r < 4; r++) {
                    int row = rb + mi * 16 + r;
                    float pv = (float)pos[row];
#pragma unroll
                    for (int ni = 0; ni < 2; ni++) {
                        float sn, cs;
                        __sincosf(pv * fr[ni], &sn, &cs);
                        float x1 = acc[mi][ni][r], x2 = acc[mi][ni + 2][r];
                        int d = ni * 16 + l15;
                        dst[(size_t)row * HD + d]      = (f16)(scale * (x1 * cs - x2 * sn));
                        dst[(size_t)row * HD + d + 32] = (f16)(scale * (x2 * cs + x1 * sn));
                    }
                }
        } else {
            // ---- V^T with mask folded in: VT[c2][s] = v * exp2(mask[s]*log2e).
            const float LOG2E = 1.4426950408889634f;
#pragma unroll
            for (int mi = 0; mi < MI; mi++) {
                float4 mv = *(const float4*)(mask + rb + mi * 16);
                float em[4];
#pragma unroll
                for (int r = 0; r < 4; r++)
                    em[r] = __builtin_amdgcn_exp2f((&mv.x)[r] * LOG2E);
#pragma unroll
                for (int ni = 0; ni < 4; ni++) {
                    int c2 = cbh - (NH + NKV) * HD + ni * 16 + l15;
                    f16x4 v4;
                    ((h16x2*)&v4)[0] = __builtin_amdgcn_cvt_pkrtz(
                        acc[mi][ni][0] * em[0], acc[mi][ni][1] * em[1]);
                    ((h16x2*)&v4)[1] = __builtin_amdgcn_cvt_pkrtz(
                        acc[mi][ni][2] * em[2], acc[mi][ni][3] * em[3]);
                    *(f16x4*)(VT + (size_t)c2 * SEQ + rb + mi * 16) = v4;
                }
            }
        }
    } else {
#pragma unroll
        for (int mi = 0; mi < MI; mi++)
#pragma unroll
            for (int ni = 0; ni < 4; ni++)
#pragma unroll
                for (int r = 0; r < 4; r++)
                    Cf[(size_t)(rb + mi * 16 + r) * N + cbh + ni * 16 + l15] =
                        acc[mi][ni][r];
    }
}

// ---------------- fused flash attention: 4 tiles per barrier, ring-8 -----------
// grid (SEQ/256, NH) = 256 blocks x 512 threads. Round-5 symmetric 8-wave
// staging (waves 0-3 K permuted-rows g(), waves 4-7 V^T; 2 async16/wave/tile).
// RING of 8 slots, ONE barrier per FOUR tiles, stage AFTER the barrier:
// iteration i stages tiles 4i+4..4i+7 (overwriting 4i-4..4i-1 — read during
// compute(i-1), which completed before the just-passed barrier(i): safe).
// The vmcnt(0) before barrier(i) drains loads issued right after
// barrier(i-1), a full 4-tile compute (~4800 cy) earlier — the drain is
// free. Barrier count 32 -> 8 (the one lever with a measured positive
// trend: each halving ~ -1..-2us; conflicts stay 0, rows 64-f16 wide).
// LDS = 132 KB (1 block/CU, unchanged from ring-6's occupancy).
__global__ __launch_bounds__(512)
void attn_fused(const f16* __restrict__ Qb, const f16* __restrict__ Kb,
                const f16* __restrict__ VTb, const float* __restrict__ mask,
                f16* __restrict__ ctx) {
    __shared__ f16 Ks[8][64 * 64];
    __shared__ f16 Vs[8][64 * 64];
    __shared__ f16 Em[SEQ];

    int t = threadIdx.x, w = t >> 6, lane = t & 63, quad = lane >> 4, l15 = lane & 15;
    int h = blockIdx.y, kvh = h >> 2;
    int qbase = blockIdx.x * 256 + w * 32;
    const f16* Qh = Qb  + (size_t)h   * SEQ * HD;
    const f16* Kh = Kb  + (size_t)kvh * SEQ * HD;
    const f16* Vh = VTb + (size_t)kvh * HD * SEQ;
    int sw = l15 & 7;
    const float LOG2E = 1.4426950408889634f;

    // ---- staging: wave role. K waves use permuted rows (g(rr)=k_eff). ----
    int r8 = lane >> 3;
    int cc = (lane & 7) ^ r8;
    bool isK = w < 4;
    int ws = isK ? w : (w - 4);
    const f16* g0;
    long gstep;
    if (isK) {
        int gk = 32 * (ws >> 1) + 4 * (ws & 1) + 8 * (r8 >> 2) + (r8 & 3);
        g0 = Kh + (size_t)gk * HD + cc * 8;
        gstep = (long)16 * HD;       // second async16: keys g+16
    } else {
        g0 = Vh + (size_t)(ws * 16 + r8) * SEQ + cc * 8;
        gstep = (long)8 * SEQ;       // second async16: rows +8
    }
    const f16* g1 = g0 + gstep;
    long adv = isK ? (long)64 * HD : 64;
    int lr0 = ws * 16 * 64, lr1 = lr0 + 8 * 64;

    {   // prologue: stage tiles 0..3 into slots 0..3
#pragma unroll
        for (int j = 0; j < 4; j++) {
            f16* dst = (isK ? &Ks[j][0] : &Vs[j][0]);
            async16(g0, dst + lr0);
            async16(g1, dst + lr1);
            if (j < 3) { g0 += adv; g1 += adv; }
        }
    }

    // ---- stage em = exp2(mask*log2e) for full SEQ (one f16x4 per thread) ----
    {
        int idx = t * 4;
        float4 mv = *(const float4*)(mask + idx);
        f16x4 e;
        ((h16x2*)&e)[0] = __builtin_amdgcn_cvt_pkrtz(
            __builtin_amdgcn_exp2f(mv.x * LOG2E), __builtin_amdgcn_exp2f(mv.y * LOG2E));
        ((h16x2*)&e)[1] = __builtin_amdgcn_cvt_pkrtz(
            __builtin_amdgcn_exp2f(mv.z * LOG2E), __builtin_amdgcn_exp2f(mv.w * LOG2E));
        *(f16x4*)(&Em[idx]) = e;
    }

    // ---- Q fragments (persistent): B-operand of S^T, n = q ----
    f16x8 bq[2][2];
#pragma unroll
    for (int qg = 0; qg < 2; qg++)
#pragma unroll
        for (int ks = 0; ks < 2; ks++)
            bq[qg][ks] = *(const f16x8*)(Qh + (size_t)(qbase + qg * 16 + l15) * HD
                                            + ks * 32 + quad * 8);

    f32x4 o[4][2] = {};          // O^T: [d-tile][q-group]
    f32x4 ol[2]   = {};          // l accumulator (all rows identical)

    int c0 = (quad ^ sw) * 8, c1 = ((4 | quad) ^ sw) * 8;

    // one-tile compute body (slot = tile's ring slot)
    auto tilecomp = [&](int tt, int slot) {
        const f16* Kb_ = &Ks[slot][0];
        const f16* Vb_ = &Vs[slot][0];
        // ---- S^T = K @ Q^T (keys in permuted order) ----
        f32x4 st[4][2] = {};
        __builtin_amdgcn_s_setprio(1);
#pragma unroll
        for (int ni = 0; ni < 4; ni++) {
            const f16* kr = Kb_ + (ni * 16 + l15) * 64;
            f16x8 ak0 = *(const f16x8*)(kr + c0);
            f16x8 ak1 = *(const f16x8*)(kr + c1);
#pragma unroll
            for (int qg = 0; qg < 2; qg++) {
                st[ni][qg] = mfma_16x16x32(ak0, bq[qg][0], st[ni][qg]);
                st[ni][qg] = mfma_16x16x32(ak1, bq[qg][1], st[ni][qg]);
            }
        }
        __builtin_amdgcn_s_setprio(0);
        // ---- p = exp2(s); pack via cvt_pkrtz ----
        f16x8 pb[2][2];
#pragma unroll
        for (int ni = 0; ni < 4; ni++)
#pragma unroll
            for (int qg = 0; qg < 2; qg++) {
                h16x2 lo = __builtin_amdgcn_cvt_pkrtz(
                    __builtin_amdgcn_exp2f(st[ni][qg][0]),
                    __builtin_amdgcn_exp2f(st[ni][qg][1]));
                h16x2 hi = __builtin_amdgcn_cvt_pkrtz(
                    __builtin_amdgcn_exp2f(st[ni][qg][2]),
                    __builtin_amdgcn_exp2f(st[ni][qg][3]));
                ((h16x2*)&pb[qg][ni >> 1])[(ni & 1) * 2]     = lo;
                ((h16x2*)&pb[qg][ni >> 1])[(ni & 1) * 2 + 1] = hi;
            }
        // ---- l += em-row @ P ----
        f16x8 em0 = *(const f16x8*)(&Em[tt * 64 + quad * 8]);
        f16x8 em1 = *(const f16x8*)(&Em[tt * 64 + 32 + quad * 8]);
        __builtin_amdgcn_s_setprio(1);
#pragma unroll
        for (int qg = 0; qg < 2; qg++) {
            ol[qg] = mfma_16x16x32(em0, pb[qg][0], ol[qg]);
            ol[qg] = mfma_16x16x32(em1, pb[qg][1], ol[qg]);
        }
        // ---- O^T += V^T @ P ----
#pragma unroll
        for (int dt = 0; dt < 4; dt++) {
            const f16* vr = Vb_ + (dt * 16 + l15) * 64;
            f16x8 av0 = *(const f16x8*)(vr + c0);
            f16x8 av1 = *(const f16x8*)(vr + c1);
#pragma unroll
            for (int qg = 0; qg < 2; qg++) {
                o[dt][qg] = mfma_16x16x32(av0, pb[qg][0], o[dt][qg]);
                o[dt][qg] = mfma_16x16x32(av1, pb[qg][1], o[dt][qg]);
            }
        }
        __builtin_amdgcn_s_setprio(0);
    };

    // Em ds_writes drained before the first barrier publishes them
    asm volatile("s_waitcnt lgkmcnt(0)" ::: "memory");

    const int NT = SEQ / 64;     // 32 tiles, 8 barrier iterations
    for (int ktl = 0; ktl < NT; ktl += 4) {
        // drain tiles ktl..ktl+3 (issued a full 4-tile compute ago — free)
        asm volatile("s_waitcnt vmcnt(0)" ::: "memory");
        __builtin_amdgcn_sched_barrier(0);
        __builtin_amdgcn_s_barrier();            // tiles ktl..ktl+3 landed
        __builtin_amdgcn_sched_barrier(0);       // pin: no ds_read hoists above

        if (ktl + 4 < NT) {
            // stage tiles ktl+4..ktl+7 (overwrite ktl-4..ktl-1: reads done
            // before the barrier we just passed)
#pragma unroll
            for (int j = 0; j < 4; j++) {
                g0 += adv; g1 += adv;
                f16* dst = (isK ? &Ks[(ktl + 4 + j) & 7][0]
                                : &Vs[(ktl + 4 + j) & 7][0]);
                async16(g0, dst + lr0);
                async16(g1, dst + lr1);
            }
        }

        tilecomp(ktl,     ktl & 7);
        tilecomp(ktl + 1, (ktl + 1) & 7);
        tilecomp(ktl + 2, (ktl + 2) & 7);
        tilecomp(ktl + 3, (ktl + 3) & 7);
    }

    // ---- normalize in-register, write ctx[row][h*64+d] directly ----
    float inv[2] = { 1.0f / ol[0][0], 1.0f / ol[1][0] };
#pragma unroll
    for (int dt = 0; dt < 4; dt++)
#pragma unroll
        for (int qg = 0; qg < 2; qg++) {
            f16x4 v4;
            ((h16x2*)&v4)[0] = __builtin_amdgcn_cvt_pkrtz(
                o[dt][qg][0] * inv[qg], o[dt][qg][1] * inv[qg]);
            ((h16x2*)&v4)[1] = __builtin_amdgcn_cvt_pkrtz(
                o[dt][qg][2] * inv[qg], o[dt][qg][3] * inv[qg]);
            *(f16x4*)(ctx + (size_t)(qbase + qg * 16 + l15) * (NH * HD)
                          + h * HD + dt * 16 + quad * 4) = v4;
        }
}

// ---------------- launch ----------------
extern "C" void kernel_launch(void* const* d_in, const int* in_sizes, int n_in,
                              void* d_out, int out_size, void* d_ws, size_t ws_size,
                              hipStream_t stream) {
    const float* x    = (const float*)d_in[0];
    const float* mask = (const float*)d_in[1];
    const int*   pos  = (const int*)  d_in[2];
    const float* wq   = (const float*)d_in[3];
    const float* wk   = (const float*)d_in[4];
    const float* wv   = (const float*)d_in[5];
    const float* wo   = (const float*)d_in[6];
    float* out = (float*)d_out;

    char* ws = (char*)d_ws;
    // phase 1-2: xb [0,8M), Wcat [8,20M), woT [20,28M), Qb [28,36M),
    //            Kb [36,38M), VTb [38,40M)
    // phase 3:   ctx [0,8M) (xb dead after gemm0)
    // phase 4:   gemm1 reads ctx + woT
    f16*   xb    = (f16*)(ws);
    f16*   Wcat  = (f16*)(ws + ((size_t)8  << 20));
    f16*   woT   = (f16*)(ws + ((size_t)20 << 20));
    f16*   Qb    = (f16*)(ws + ((size_t)28 << 20));
    f16*   Kb    = (f16*)(ws + ((size_t)36 << 20));
    f16*   VTb   = (f16*)(ws + ((size_t)38 << 20));
    f16*   ctx   = (f16*)(ws);

    prep_all<<<dim3(32, 32, 5), 256, 0, stream>>>(
        x, wq, wk, wv, wo, xb, Wcat, woT);

    // fused Q/K/V projection + RoPE + mask-folded V: C[2048,3072] = xb @ Wcat^T
    gemm_bt<0, 64><<<dim3(3072 / 128, 2048 / 64), 256, 0, stream>>>(
        xb, Wcat, nullptr, Qb, Kb, VTb, pos, mask, 3072, 2048);

    attn_fused<<<dim3(SEQ / 256, NH), 512, 0, stream>>>(
        Qb, Kb, VTb, mask, ctx);

    // out = ctx @ wo (fp32 direct)
    gemm_bt<1, 64><<<dim3(2048 / 128, 2048 / 64), 256, 0, stream>>>(
        ctx, woT, out, nullptr, nullptr, nullptr, nullptr, nullptr, 2048, 2048);
}